// Round 3
// baseline (354.452 us; speedup 1.0000x reference)
//
#include <hip/hip_runtime.h>
#include <hip/hip_bf16.h>
#include <hip/hip_cooperative_groups.h>

namespace cg = cooperative_groups;

#define SEP_ID 2
#define S_LEN  4096
#define HID    768
#define MAXS   64

using short8  = __attribute__((ext_vector_type(8))) short;  // 8 bf16 (4 VGPRs)
using floatx4 = __attribute__((ext_vector_type(4))) float;  // MFMA accumulator

struct Params {
    const float* hidden; const int* ids;
    const float* W1; const float* b1;
    const float* W2; const float* b2;
    const float* W3; const float* b3;
    float* out;
    int* sent_start; int* sent_cnt;
    __hip_bfloat16* sentb; __hip_bfloat16* W1T; __hip_bfloat16* W2T;
    __hip_bfloat16* x1; float* part;
};

__device__ __forceinline__ float gelu_exact(float x) {
    return 0.5f * x * (1.0f + erff(x * 0.70710678118654752f));
}

// One cooperative kernel, 256 blocks x 384 threads (1 block/CU guaranteed:
// 18.4KB LDS, <=256 VGPR). Phases separated by grid.sync(). All __syncthreads
// are executed by all 384 threads (work is guarded, barriers are not).
__global__ __launch_bounds__(384) void mega_kernel(Params p) {
    cg::grid_group grid = cg::this_grid();
    const int blk = blockIdx.x;
    const int t = threadIdx.x;

    __shared__ __align__(16) char smem[18688];   // union across phases

    // ================= Phase A: bounds (blocks 0-7) || tconv (blocks 8-255)
    if (blk < 8) {
        int* cnts = (int*)smem;          // 256
        int* offs = cnts + 256;          // 256
        int* sep_pos = offs + 256;       // 4096
        int* totalp = sep_pos + 4096;    // 1   (total 18436 B)
        const int* row = p.ids + (size_t)blk * S_LEN;
        int local[16]; int c = 0;
        if (t < 256) {
            const int base = t * 16;
            #pragma unroll
            for (int i = 0; i < 16; ++i)
                if (row[base + i] == SEP_ID) local[c++] = base + i;
            cnts[t] = c;
        }
        __syncthreads();
        if (t == 0) {
            int s = 0;
            for (int i = 0; i < 256; ++i) { offs[i] = s; s += cnts[i]; }
            *totalp = s;
        }
        __syncthreads();
        if (t < 256) { int o = offs[t]; for (int i = 0; i < c; ++i) sep_pos[o + i] = local[i]; }
        __syncthreads();
        const int n_sep = *totalp;
        if (t < MAXS) {
            const int m = t;
            int start = 0, cnt = 0;
            if (n_sep == 0) {
                if (m == 0) { start = 0; cnt = S_LEN; }
            } else if (m < n_sep) {
                if (m == 0) { start = 0; cnt = sep_pos[0] + 1; }     // includes first sep
                else { start = sep_pos[m - 1] + 1; cnt = sep_pos[m] - sep_pos[m - 1] - 1; }
            } else if (m == n_sep) {
                start = sep_pos[n_sep - 1] + 1;                      // trailing segment
                cnt = (S_LEN - 1) - start;                           // excludes token S-1
                if (cnt < 0) cnt = 0;
            }
            p.sent_start[blk * MAXS + m] = start;
            p.sent_cnt[blk * MAXS + m]  = cnt;
        }
    } else {
        // weight transposes fp32[K][N] -> bf16[N][K]; 4096 tiles over 248 blocks
        float* tile = (float*)smem;               // [32][33]
        const int c = t & 31;
        const int r = t >> 5;                      // valid rows when t<256
        for (int id0 = blk - 8; id0 < 4096; id0 += 248) {
            const float* in; __hip_bfloat16* outw; int K, N, n0, k0;
            if (id0 < 3072) { in = p.W1; outw = p.W1T; K = 768;  N = 4096;
                              n0 = (id0 & 127) * 32; k0 = (id0 >> 7) * 32; }
            else { const int id = id0 - 3072;
                   in = p.W2; outw = p.W2T; K = 4096; N = 256;
                   n0 = (id & 7) * 32; k0 = (id >> 3) * 32; }
            if (t < 256) {
                #pragma unroll
                for (int i = 0; i < 32; i += 8)
                    tile[(r + i) * 33 + c] = in[(size_t)(k0 + r + i) * N + n0 + c];
            }
            __syncthreads();
            if (t < 256) {
                #pragma unroll
                for (int i = 0; i < 32; i += 8)
                    outw[(size_t)(n0 + r + i) * K + k0 + c] = __float2bfloat16(tile[c * 33 + r + i]);
            }
            __syncthreads();
        }
    }

    grid.sync();

    // ================= Phase B: pool (2 sentences per block, 192 thr each)
    {
        const int which = t / 192;                 // 0 or 1
        const int u = t - which * 192;             // float4 column
        const int sidx = blk * 2 + which;          // 0..511
        const int b = sidx >> 6;
        const int start = p.sent_start[sidx];
        const int cnt   = p.sent_cnt[sidx];
        const float4* base = (const float4*)(p.hidden + ((size_t)b * S_LEN + start) * HID);
        float ax = 0.f, ay = 0.f, az = 0.f, aw = 0.f;
        int i = 0;
        for (; i + 8 <= cnt; i += 8) {             // 8 x 16B in flight per thread
            float4 v[8];
            #pragma unroll
            for (int j = 0; j < 8; ++j) v[j] = base[(size_t)(i + j) * 192 + u];
            #pragma unroll
            for (int j = 0; j < 8; ++j) { ax += v[j].x; ay += v[j].y; az += v[j].z; aw += v[j].w; }
        }
        for (; i < cnt; ++i) {
            float4 v = base[(size_t)i * 192 + u];
            ax += v.x; ay += v.y; az += v.z; aw += v.w;
        }
        const float inv = (cnt > 0) ? 1.0f / (float)cnt : 0.0f;
        __hip_bfloat16* o = p.sentb + (size_t)sidx * HID + u * 4;
        o[0] = __float2bfloat16(ax * inv);
        o[1] = __float2bfloat16(ay * inv);
        o[2] = __float2bfloat16(az * inv);
        o[3] = __float2bfloat16(aw * inv);
    }

    grid.sync();

    // ================= Phase C: gemm1  x1 = GELU(sentb[512,768] @ W1T^T + b1)
    // 64(M)x128(N) tile, BK=32, waves 0-3 in 2x2, each 32x64 (2x4 MFMA).
    {
        const int n0 = (blk & 31) * 128;
        const int m0 = (blk >> 5) * 64;
        const int w = t >> 6, l = t & 63;
        const int wm = (w >> 1) * 32;
        const int wn = (w & 1) * 64;
        __hip_bfloat16* Al = (__hip_bfloat16*)smem;    // [64][40]
        __hip_bfloat16* Bl = Al + 64 * 40;             // [128][40]
        floatx4 acc[2][4] = {};
        const int r  = t >> 2;
        const int ch = (t & 3) * 8;
        const __hip_bfloat16 *Ag = nullptr, *Bg0 = nullptr, *Bg1 = nullptr;
        if (t < 256) {
            Ag  = p.sentb + (size_t)(m0 + r) * 768 + ch;
            Bg0 = p.W1T + (size_t)(n0 + r) * 768 + ch;
            Bg1 = p.W1T + (size_t)(n0 + 64 + r) * 768 + ch;
        }
        const int lr = l & 15;
        const int kq = (l >> 4) * 8;
        for (int k0 = 0; k0 < 768; k0 += 32) {
            short8 av, bv0, bv1;
            if (t < 256) {
                av  = *(const short8*)(Ag  + k0);
                bv0 = *(const short8*)(Bg0 + k0);
                bv1 = *(const short8*)(Bg1 + k0);
            }
            __syncthreads();                 // prior iter's frag reads done
            if (t < 256) {
                *(short8*)(Al + r * 40 + ch)        = av;
                *(short8*)(Bl + r * 40 + ch)        = bv0;
                *(short8*)(Bl + (64 + r) * 40 + ch) = bv1;
            }
            __syncthreads();
            if (t < 256) {
                short8 a0 = *(const short8*)(Al + (wm + lr) * 40 + kq);
                short8 a1 = *(const short8*)(Al + (wm + 16 + lr) * 40 + kq);
                #pragma unroll
                for (int j = 0; j < 4; ++j) {
                    short8 bj = *(const short8*)(Bl + (wn + j * 16 + lr) * 40 + kq);
                    acc[0][j] = __builtin_amdgcn_mfma_f32_16x16x32_bf16(a0, bj, acc[0][j], 0, 0, 0);
                    acc[1][j] = __builtin_amdgcn_mfma_f32_16x16x32_bf16(a1, bj, acc[1][j], 0, 0, 0);
                }
            }
        }
        if (t < 256) {
            #pragma unroll
            for (int i = 0; i < 2; ++i) {
                #pragma unroll
                for (int j = 0; j < 4; ++j) {
                    const int col  = n0 + wn + j * 16 + lr;
                    const int rowb = m0 + wm + i * 16 + (l >> 4) * 4;
                    const float bv = p.b1[col];
                    #pragma unroll
                    for (int rg = 0; rg < 4; ++rg) {
                        float x = acc[i][j][rg] + bv;
                        p.x1[(size_t)(rowb + rg) * 4096 + col] = __float2bfloat16(gelu_exact(x));
                    }
                }
            }
        }
    }

    grid.sync();

    // ================= Phase D: gemm2 split-K=8 partials (64x64 tile)
    {
        const int n0 = (blk & 3) * 64;
        const int m0 = ((blk >> 2) & 7) * 64;
        const int s  = blk >> 5;
        const int kb = s * 512;
        const int w = t >> 6, l = t & 63;
        const int wm = (w >> 1) * 32;
        const int wn = (w & 1) * 32;
        __hip_bfloat16* Al = (__hip_bfloat16*)smem;    // [64][40]
        __hip_bfloat16* Bl = Al + 64 * 40;             // [64][40]
        floatx4 acc[2][2] = {};
        const int r  = t >> 2;
        const int ch = (t & 3) * 8;
        const __hip_bfloat16 *Ag = nullptr, *Bg = nullptr;
        if (t < 256) {
            Ag = p.x1  + (size_t)(m0 + r) * 4096 + kb + ch;
            Bg = p.W2T + (size_t)(n0 + r) * 4096 + kb + ch;
        }
        const int lr = l & 15;
        const int kq = (l >> 4) * 8;
        for (int k0 = 0; k0 < 512; k0 += 32) {
            short8 av, bv;
            if (t < 256) { av = *(const short8*)(Ag + k0); bv = *(const short8*)(Bg + k0); }
            __syncthreads();
            if (t < 256) {
                *(short8*)(Al + r * 40 + ch) = av;
                *(short8*)(Bl + r * 40 + ch) = bv;
            }
            __syncthreads();
            if (t < 256) {
                short8 a0 = *(const short8*)(Al + (wm + lr) * 40 + kq);
                short8 a1 = *(const short8*)(Al + (wm + 16 + lr) * 40 + kq);
                short8 b0 = *(const short8*)(Bl + (wn + lr) * 40 + kq);
                short8 b1 = *(const short8*)(Bl + (wn + 16 + lr) * 40 + kq);
                acc[0][0] = __builtin_amdgcn_mfma_f32_16x16x32_bf16(a0, b0, acc[0][0], 0, 0, 0);
                acc[0][1] = __builtin_amdgcn_mfma_f32_16x16x32_bf16(a0, b1, acc[0][1], 0, 0, 0);
                acc[1][0] = __builtin_amdgcn_mfma_f32_16x16x32_bf16(a1, b0, acc[1][0], 0, 0, 0);
                acc[1][1] = __builtin_amdgcn_mfma_f32_16x16x32_bf16(a1, b1, acc[1][1], 0, 0, 0);
            }
        }
        if (t < 256) {
            float* po = p.part + (size_t)s * 512 * 256;
            #pragma unroll
            for (int i = 0; i < 2; ++i) {
                #pragma unroll
                for (int j = 0; j < 2; ++j) {
                    const int col  = n0 + wn + j * 16 + lr;
                    const int rowb = m0 + wm + i * 16 + (l >> 4) * 4;
                    #pragma unroll
                    for (int rg = 0; rg < 4; ++rg)
                        po[(size_t)(rowb + rg) * 256 + col] = acc[i][j][rg];
                }
            }
        }
    }

    grid.sync();

    // ================= Phase E: reduce partials + b2 + GELU + head (2 rows/blk)
    {
        float* r0 = (float*)smem;
        float* r1 = r0 + 4;
        for (int rr = 0; rr < 2; ++rr) {
            const int row = blk * 2 + rr;
            float y0 = 0.f, y1 = 0.f;
            if (t < 256) {
                float s = 0.f;
                #pragma unroll
                for (int k = 0; k < 8; ++k)
                    s += p.part[((size_t)k * 512 + row) * 256 + t];
                const float x = gelu_exact(s + p.b2[t]);
                y0 = x * p.W3[t * 2 + 0];
                y1 = x * p.W3[t * 2 + 1];
                #pragma unroll
                for (int off = 32; off; off >>= 1) {
                    y0 += __shfl_down(y0, off);
                    y1 += __shfl_down(y1, off);
                }
            }
            __syncthreads();
            if (t < 256 && (t & 63) == 0) { r0[t >> 6] = y0; r1[t >> 6] = y1; }
            __syncthreads();
            if (t == 0) p.out[row * 2 + 0] = r0[0] + r0[1] + r0[2] + r0[3] + p.b3[0];
            if (t == 1) p.out[row * 2 + 1] = r1[0] + r1[1] + r1[2] + r1[3] + p.b3[1];
            __syncthreads();
        }
    }
}

// ---------------------------------------------------------------------------
extern "C" void kernel_launch(void* const* d_in, const int* in_sizes, int n_in,
                              void* d_out, int out_size, void* d_ws, size_t ws_size,
                              hipStream_t stream) {
    char* ws = (char*)d_ws;
    Params prm;
    prm.hidden = (const float*)d_in[0];
    prm.ids    = (const int*)d_in[1];
    prm.W1     = (const float*)d_in[2];
    prm.b1     = (const float*)d_in[3];
    prm.W2     = (const float*)d_in[4];
    prm.b2     = (const float*)d_in[5];
    prm.W3     = (const float*)d_in[6];
    prm.b3     = (const float*)d_in[7];
    prm.out    = (float*)d_out;
    prm.sent_start = (int*)(ws + 0);                          // 2 KB
    prm.sent_cnt   = (int*)(ws + 2048);                       // 2 KB
    prm.sentb      = (__hip_bfloat16*)(ws + 4096);            // 512x768 bf16
    prm.W1T        = (__hip_bfloat16*)(ws + 790528);          // 4096x768 bf16
    prm.W2T        = (__hip_bfloat16*)(ws + 7081984);         // 256x4096 bf16
    prm.x1         = (__hip_bfloat16*)(ws + 9179136);         // 512x4096 bf16
    prm.part       = (float*)(ws + 13373440);                 // 8x512x256 f32
    // total ws use: ~17.6 MB

    void* kargs[] = { (void*)&prm };
    hipLaunchCooperativeKernel((const void*)mega_kernel, dim3(256), dim3(384),
                               kargs, 0, stream);
}

// Round 4
// 198.982 us; speedup vs baseline: 1.7813x; 1.7813x over previous
//
#include <hip/hip_runtime.h>
#include <hip/hip_bf16.h>

#define SEP_ID 2
#define S_LEN  4096
#define HID    768
#define MAXS   64

using short8  = __attribute__((ext_vector_type(8))) short;  // 8 bf16 (4 VGPRs)
using floatx4 = __attribute__((ext_vector_type(4))) float;  // MFMA accumulator

__device__ __forceinline__ float gelu_exact(float x) {
    return 0.5f * x * (1.0f + erff(x * 0.70710678118654752f));
}

// ---------------------------------------------------------------------------
// K1: bounds (blocks 0-7) + weight transposes (blocks 8-4103) in one launch.
// bounds uses a shfl prefix-scan (no serial 256-loop).
// tconv: fp32[K][N] -> bf16[N][K], one 32x32 tile per block.
// ---------------------------------------------------------------------------
__global__ __launch_bounds__(256) void prep_kernel(const int* __restrict__ ids,
                                                   const float* __restrict__ W1,
                                                   const float* __restrict__ W2,
                                                   __hip_bfloat16* __restrict__ W1T,
                                                   __hip_bfloat16* __restrict__ W2T,
                                                   int* __restrict__ sent_start,
                                                   int* __restrict__ sent_cnt) {
    __shared__ __align__(16) char smem[16896];
    const int blk = blockIdx.x;
    const int t = threadIdx.x;

    if (blk < 8) {
        int* sep_pos = (int*)smem;            // 4096 ints
        int* wtot    = sep_pos + 4096;        // 4 ints
        const int b = blk;
        const int* row = ids + (size_t)b * S_LEN;
        const int lane = t & 63, w = t >> 6;

        int local[16]; int c = 0;
        const int base = t * 16;
        #pragma unroll
        for (int q = 0; q < 4; ++q) {
            int4 v = ((const int4*)row)[t * 4 + q];
            if (v.x == SEP_ID) local[c++] = base + q * 4 + 0;
            if (v.y == SEP_ID) local[c++] = base + q * 4 + 1;
            if (v.z == SEP_ID) local[c++] = base + q * 4 + 2;
            if (v.w == SEP_ID) local[c++] = base + q * 4 + 3;
        }
        // inclusive prefix within wave, then block offset via wave totals
        int scan = c;
        #pragma unroll
        for (int off = 1; off < 64; off <<= 1) {
            int n = __shfl_up(scan, off);
            if (lane >= off) scan += n;
        }
        if (lane == 63) wtot[w] = scan;
        __syncthreads();
        int wbase = 0;
        for (int i = 0; i < w; ++i) wbase += wtot[i];
        const int o = wbase + scan - c;
        for (int i = 0; i < c; ++i) sep_pos[o + i] = local[i];
        __syncthreads();
        const int n_sep = wtot[0] + wtot[1] + wtot[2] + wtot[3];

        if (t < MAXS) {
            const int m = t;
            int start = 0, cnt = 0;
            if (n_sep == 0) {
                if (m == 0) { start = 0; cnt = S_LEN; }
            } else if (m < n_sep) {
                if (m == 0) { start = 0; cnt = sep_pos[0] + 1; }     // includes first sep
                else { start = sep_pos[m - 1] + 1; cnt = sep_pos[m] - sep_pos[m - 1] - 1; }
            } else if (m == n_sep) {
                start = sep_pos[n_sep - 1] + 1;                      // trailing segment
                cnt = (S_LEN - 1) - start;                           // excludes token S-1
                if (cnt < 0) cnt = 0;
            }
            sent_start[b * MAXS + m] = start;
            sent_cnt[b * MAXS + m]  = cnt;
        }
    } else {
        float* tile = (float*)smem;           // [32][33]
        const int id0 = blk - 8;
        const float* in; __hip_bfloat16* outw; int K, N, n0, k0;
        if (id0 < 3072) { in = W1; outw = W1T; K = 768;  N = 4096;
                          n0 = (id0 & 127) * 32; k0 = (id0 >> 7) * 32; }
        else { const int id = id0 - 3072;
               in = W2; outw = W2T; K = 4096; N = 256;
               n0 = (id & 7) * 32; k0 = (id >> 3) * 32; }
        const int c = t & 31;
        const int r = t >> 5;
        #pragma unroll
        for (int i = 0; i < 32; i += 8)
            tile[(r + i) * 33 + c] = in[(size_t)(k0 + r + i) * N + n0 + c];
        __syncthreads();
        #pragma unroll
        for (int i = 0; i < 32; i += 8)
            outw[(size_t)(n0 + r + i) * K + k0 + c] = __float2bfloat16(tile[c * 33 + r + i]);
    }
}

// ---------------------------------------------------------------------------
// K2: per-sentence mean pooling. 512 blocks x 192 threads, float4 columns,
// 8-row unroll -> 8 x 16B loads in flight per thread.
// ---------------------------------------------------------------------------
__global__ __launch_bounds__(192) void pool_kernel(const float* __restrict__ hidden,
                                                   const int* __restrict__ sent_start,
                                                   const int* __restrict__ sent_cnt,
                                                   __hip_bfloat16* __restrict__ sent) {
    const int blk = blockIdx.x;
    const int b = blk >> 6;
    const int t = threadIdx.x;
    const int start = sent_start[blk];
    const int cnt   = sent_cnt[blk];

    const float4* base = (const float4*)(hidden + ((size_t)b * S_LEN + start) * HID);
    float ax = 0.f, ay = 0.f, az = 0.f, aw = 0.f;
    int i = 0;
    for (; i + 8 <= cnt; i += 8) {
        float4 v[8];
        #pragma unroll
        for (int j = 0; j < 8; ++j) v[j] = base[(size_t)(i + j) * 192 + t];
        #pragma unroll
        for (int j = 0; j < 8; ++j) { ax += v[j].x; ay += v[j].y; az += v[j].z; aw += v[j].w; }
    }
    for (; i < cnt; ++i) {
        float4 v = base[(size_t)i * 192 + t];
        ax += v.x; ay += v.y; az += v.z; aw += v.w;
    }
    const float inv = (cnt > 0) ? 1.0f / (float)cnt : 0.0f;
    __hip_bfloat16* o = sent + (size_t)blk * HID + t * 4;
    o[0] = __float2bfloat16(ax * inv);
    o[1] = __float2bfloat16(ay * inv);
    o[2] = __float2bfloat16(az * inv);
    o[3] = __float2bfloat16(aw * inv);
}

// ---------------------------------------------------------------------------
// K3: GEMM1  x1 = GELU(sentb[512,768] @ W1T[4096,768]^T + b1), bf16 out.
// 64x64 tile, BK=64 (12 K-iters), grid (64,8)=512 blocks (2/CU for overlap).
// 4 waves in 2x2; each wave 32x32 via 2x2 MFMA x 2 k-steps = 8 MFMA/iter.
// LDS stride 72 bf16 (pad 8, keeps 16B alignment; 36-dword rows -> 2-way max).
// ---------------------------------------------------------------------------
__global__ __launch_bounds__(256) void gemm1_kernel(const __hip_bfloat16* __restrict__ A,
                                                    const __hip_bfloat16* __restrict__ BT,
                                                    const float* __restrict__ bias,
                                                    __hip_bfloat16* __restrict__ out) {
    const int n0 = blockIdx.x * 64;
    const int m0 = blockIdx.y * 64;
    const int t = threadIdx.x;
    const int w = t >> 6, l = t & 63;
    const int wm = (w >> 1) * 32;
    const int wn = (w & 1) * 32;

    __shared__ __hip_bfloat16 Al[64][72];
    __shared__ __hip_bfloat16 Bl[64][72];

    floatx4 acc[2][2] = {};

    const int r  = t >> 2;            // 0..63
    const int ch = (t & 3) * 16;      // 0,16,32,48
    const __hip_bfloat16* Ag = A  + (size_t)(m0 + r) * 768 + ch;
    const __hip_bfloat16* Bg = BT + (size_t)(n0 + r) * 768 + ch;

    const int lr = l & 15;
    const int kq = (l >> 4) * 8;

    for (int k0 = 0; k0 < 768; k0 += 64) {
        short8 av0 = *(const short8*)(Ag + k0);
        short8 av1 = *(const short8*)(Ag + k0 + 8);
        short8 bv0 = *(const short8*)(Bg + k0);
        short8 bv1 = *(const short8*)(Bg + k0 + 8);
        __syncthreads();
        *(short8*)(&Al[r][ch])     = av0;
        *(short8*)(&Al[r][ch + 8]) = av1;
        *(short8*)(&Bl[r][ch])     = bv0;
        *(short8*)(&Bl[r][ch + 8]) = bv1;
        __syncthreads();

        #pragma unroll
        for (int ks = 0; ks < 64; ks += 32) {
            short8 a0 = *(const short8*)(&Al[wm + lr][ks + kq]);
            short8 a1 = *(const short8*)(&Al[wm + 16 + lr][ks + kq]);
            short8 b0 = *(const short8*)(&Bl[wn + lr][ks + kq]);
            short8 b1 = *(const short8*)(&Bl[wn + 16 + lr][ks + kq]);
            acc[0][0] = __builtin_amdgcn_mfma_f32_16x16x32_bf16(a0, b0, acc[0][0], 0, 0, 0);
            acc[0][1] = __builtin_amdgcn_mfma_f32_16x16x32_bf16(a0, b1, acc[0][1], 0, 0, 0);
            acc[1][0] = __builtin_amdgcn_mfma_f32_16x16x32_bf16(a1, b0, acc[1][0], 0, 0, 0);
            acc[1][1] = __builtin_amdgcn_mfma_f32_16x16x32_bf16(a1, b1, acc[1][1], 0, 0, 0);
        }
    }

    #pragma unroll
    for (int i = 0; i < 2; ++i) {
        #pragma unroll
        for (int j = 0; j < 2; ++j) {
            const int col  = n0 + wn + j * 16 + lr;
            const int rowb = m0 + wm + i * 16 + (l >> 4) * 4;
            const float bv = bias[col];
            #pragma unroll
            for (int rg = 0; rg < 4; ++rg) {
                float x = acc[i][j][rg] + bv;
                out[(size_t)(rowb + rg) * 4096 + col] = __float2bfloat16(gelu_exact(x));
            }
        }
    }
}

// ---------------------------------------------------------------------------
// K4: GEMM2 partials: part[s] = x1[512, 256-slice] @ W2T[256, 256-slice]^T.
// Split-K=16 (256 K each), BK=64 -> 4 K-iters. Grid (4,8,16)=512 blocks.
// ---------------------------------------------------------------------------
__global__ __launch_bounds__(256) void gemm2_kernel(const __hip_bfloat16* __restrict__ A,
                                                    const __hip_bfloat16* __restrict__ BT,
                                                    float* __restrict__ part) {
    const int n0 = blockIdx.x * 64;
    const int m0 = blockIdx.y * 64;
    const int s  = blockIdx.z;
    const int kb = s * 256;
    const int t = threadIdx.x;
    const int w = t >> 6, l = t & 63;
    const int wm = (w >> 1) * 32;
    const int wn = (w & 1) * 32;

    __shared__ __hip_bfloat16 Al[64][72];
    __shared__ __hip_bfloat16 Bl[64][72];

    floatx4 acc[2][2] = {};

    const int r  = t >> 2;
    const int ch = (t & 3) * 16;
    const __hip_bfloat16* Ag = A  + (size_t)(m0 + r) * 4096 + kb + ch;
    const __hip_bfloat16* Bg = BT + (size_t)(n0 + r) * 4096 + kb + ch;

    const int lr = l & 15;
    const int kq = (l >> 4) * 8;

    for (int k0 = 0; k0 < 256; k0 += 64) {
        short8 av0 = *(const short8*)(Ag + k0);
        short8 av1 = *(const short8*)(Ag + k0 + 8);
        short8 bv0 = *(const short8*)(Bg + k0);
        short8 bv1 = *(const short8*)(Bg + k0 + 8);
        __syncthreads();
        *(short8*)(&Al[r][ch])     = av0;
        *(short8*)(&Al[r][ch + 8]) = av1;
        *(short8*)(&Bl[r][ch])     = bv0;
        *(short8*)(&Bl[r][ch + 8]) = bv1;
        __syncthreads();

        #pragma unroll
        for (int ks = 0; ks < 64; ks += 32) {
            short8 a0 = *(const short8*)(&Al[wm + lr][ks + kq]);
            short8 a1 = *(const short8*)(&Al[wm + 16 + lr][ks + kq]);
            short8 b0 = *(const short8*)(&Bl[wn + lr][ks + kq]);
            short8 b1 = *(const short8*)(&Bl[wn + 16 + lr][ks + kq]);
            acc[0][0] = __builtin_amdgcn_mfma_f32_16x16x32_bf16(a0, b0, acc[0][0], 0, 0, 0);
            acc[0][1] = __builtin_amdgcn_mfma_f32_16x16x32_bf16(a0, b1, acc[0][1], 0, 0, 0);
            acc[1][0] = __builtin_amdgcn_mfma_f32_16x16x32_bf16(a1, b0, acc[1][0], 0, 0, 0);
            acc[1][1] = __builtin_amdgcn_mfma_f32_16x16x32_bf16(a1, b1, acc[1][1], 0, 0, 0);
        }
    }

    float* po = part + (size_t)s * 512 * 256;
    #pragma unroll
    for (int i = 0; i < 2; ++i) {
        #pragma unroll
        for (int j = 0; j < 2; ++j) {
            const int col  = n0 + wn + j * 16 + lr;
            const int rowb = m0 + wm + i * 16 + (l >> 4) * 4;
            #pragma unroll
            for (int rg = 0; rg < 4; ++rg)
                po[(size_t)(rowb + rg) * 256 + col] = acc[i][j][rg];
        }
    }
}

// ---------------------------------------------------------------------------
// K5: fused reduce(16 split-K partials) + b2 + GELU + head (W3[256,2]+b3).
// ---------------------------------------------------------------------------
__global__ __launch_bounds__(256) void rh_kernel(const float* __restrict__ part,
                                                 const float* __restrict__ b2,
                                                 const float* __restrict__ W3,
                                                 const float* __restrict__ b3,
                                                 float* __restrict__ out) {
    const int row = blockIdx.x;     // 512
    const int c = threadIdx.x;      // 256
    const int w = c >> 6, l = c & 63;

    float s = 0.f;
    #pragma unroll
    for (int k = 0; k < 16; ++k)
        s += part[((size_t)k * 512 + row) * 256 + c];
    const float x = gelu_exact(s + b2[c]);
    float y0 = x * W3[c * 2 + 0];
    float y1 = x * W3[c * 2 + 1];
    #pragma unroll
    for (int off = 32; off; off >>= 1) {
        y0 += __shfl_down(y0, off);
        y1 += __shfl_down(y1, off);
    }
    __shared__ float r0[4], r1[4];
    if (l == 0) { r0[w] = y0; r1[w] = y1; }
    __syncthreads();
    if (c == 0) out[row * 2 + 0] = r0[0] + r0[1] + r0[2] + r0[3] + b3[0];
    if (c == 1) out[row * 2 + 1] = r1[0] + r1[1] + r1[2] + r1[3] + b3[1];
}

// ---------------------------------------------------------------------------
extern "C" void kernel_launch(void* const* d_in, const int* in_sizes, int n_in,
                              void* d_out, int out_size, void* d_ws, size_t ws_size,
                              hipStream_t stream) {
    const float* hidden = (const float*)d_in[0];
    const int*   ids    = (const int*)d_in[1];
    const float* W1     = (const float*)d_in[2];
    const float* b1     = (const float*)d_in[3];
    const float* W2     = (const float*)d_in[4];
    const float* b2     = (const float*)d_in[5];
    const float* W3     = (const float*)d_in[6];
    const float* b3     = (const float*)d_in[7];
    float* out = (float*)d_out;

    char* ws = (char*)d_ws;
    int* sent_start        = (int*)(ws + 0);                      // 2 KB
    int* sent_cnt          = (int*)(ws + 2048);                   // 2 KB
    __hip_bfloat16* sentb  = (__hip_bfloat16*)(ws + 4096);        // 512x768 bf16
    __hip_bfloat16* W1T    = (__hip_bfloat16*)(ws + 790528);      // 4096x768 bf16
    __hip_bfloat16* W2T    = (__hip_bfloat16*)(ws + 7081984);     // 256x4096 bf16
    __hip_bfloat16* x1     = (__hip_bfloat16*)(ws + 9179136);     // 512x4096 bf16
    float* part            = (float*)(ws + 13373440);             // 16x512x256 f32
    // total ws use: ~21.8 MB

    prep_kernel<<<4104, 256, 0, stream>>>(ids, W1, W2, W1T, W2T, sent_start, sent_cnt);
    pool_kernel<<<512, 192, 0, stream>>>(hidden, sent_start, sent_cnt, sentb);
    gemm1_kernel<<<dim3(64, 8), 256, 0, stream>>>(sentb, W1T, b1, x1);
    gemm2_kernel<<<dim3(4, 8, 16), 256, 0, stream>>>(x1, W2T, part);
    rh_kernel<<<512, 256, 0, stream>>>(part, b2, W3, b3, out);
}

// Round 5
// 195.352 us; speedup vs baseline: 1.8144x; 1.0186x over previous
//
#include <hip/hip_runtime.h>
#include <hip/hip_bf16.h>

#define SEP_ID 2
#define S_LEN  4096
#define HID    768
#define MAXS   64

using short8  = __attribute__((ext_vector_type(8))) short;  // 8 bf16 (4 VGPRs)
using floatx4 = __attribute__((ext_vector_type(4))) float;  // MFMA accumulator

__device__ __forceinline__ float gelu_exact(float x) {
    return 0.5f * x * (1.0f + erff(x * 0.70710678118654752f));
}

// ---------------------------------------------------------------------------
// K1 "stage1": pool blocks [0,512) + weight-transpose blocks [512,4608).
// Pool blocks are self-contained: each recomputes its sentence's bounds from
// ids via a shfl prefix-scan (validated R4), then mean-pools with float4
// columns and an 8-row unroll (8x16B loads in flight per thread).
// Pool blocks lead the grid so they dispatch first; tconv tiles fill behind.
// ---------------------------------------------------------------------------
__global__ __launch_bounds__(256) void stage1_kernel(const int* __restrict__ ids,
                                                     const float* __restrict__ hidden,
                                                     const float* __restrict__ W1,
                                                     const float* __restrict__ W2,
                                                     __hip_bfloat16* __restrict__ W1T,
                                                     __hip_bfloat16* __restrict__ W2T,
                                                     __hip_bfloat16* __restrict__ sentb) {
    __shared__ __align__(16) char smem[16640];
    const int blk = blockIdx.x;
    const int t = threadIdx.x;

    if (blk < 512) {
        // ---- self-bounds: find this row's sep positions ----
        int* sep_pos = (int*)smem;            // 4096 ints
        int* wtot    = sep_pos + 4096;        // 4 ints
        const int sidx = blk;
        const int b = sidx >> 6, m = sidx & 63;
        const int* row = ids + (size_t)b * S_LEN;
        const int lane = t & 63, w = t >> 6;

        int local[16]; int c = 0;
        const int base = t * 16;
        #pragma unroll
        for (int q = 0; q < 4; ++q) {
            int4 v = ((const int4*)row)[t * 4 + q];
            if (v.x == SEP_ID) local[c++] = base + q * 4 + 0;
            if (v.y == SEP_ID) local[c++] = base + q * 4 + 1;
            if (v.z == SEP_ID) local[c++] = base + q * 4 + 2;
            if (v.w == SEP_ID) local[c++] = base + q * 4 + 3;
        }
        int scan = c;                              // inclusive wave prefix
        #pragma unroll
        for (int off = 1; off < 64; off <<= 1) {
            int n = __shfl_up(scan, off);
            if (lane >= off) scan += n;
        }
        if (lane == 63) wtot[w] = scan;
        __syncthreads();
        int wbase = 0;
        for (int i = 0; i < w; ++i) wbase += wtot[i];
        const int o = wbase + scan - c;
        for (int i = 0; i < c; ++i) sep_pos[o + i] = local[i];
        __syncthreads();
        const int n_sep = wtot[0] + wtot[1] + wtot[2] + wtot[3];

        // ---- reference segment semantics (every thread computes) ----
        int start = 0, cnt = 0;
        if (n_sep == 0) {
            if (m == 0) { start = 0; cnt = S_LEN; }
        } else if (m < n_sep) {
            if (m == 0) { start = 0; cnt = sep_pos[0] + 1; }     // includes first sep
            else { start = sep_pos[m - 1] + 1; cnt = sep_pos[m] - sep_pos[m - 1] - 1; }
        } else if (m == n_sep) {
            start = sep_pos[n_sep - 1] + 1;                      // trailing segment
            cnt = (S_LEN - 1) - start;                           // excludes token S-1
            if (cnt < 0) cnt = 0;
        }

        // ---- mean pool: 192 threads own one float4 column each ----
        if (t < 192) {
            const float4* bp = (const float4*)(hidden + ((size_t)b * S_LEN + start) * HID);
            float ax = 0.f, ay = 0.f, az = 0.f, aw = 0.f;
            int i = 0;
            for (; i + 8 <= cnt; i += 8) {
                float4 v[8];
                #pragma unroll
                for (int j = 0; j < 8; ++j) v[j] = bp[(size_t)(i + j) * 192 + t];
                #pragma unroll
                for (int j = 0; j < 8; ++j) { ax += v[j].x; ay += v[j].y; az += v[j].z; aw += v[j].w; }
            }
            for (; i < cnt; ++i) {
                float4 v = bp[(size_t)i * 192 + t];
                ax += v.x; ay += v.y; az += v.z; aw += v.w;
            }
            const float inv = (cnt > 0) ? 1.0f / (float)cnt : 0.0f;
            __hip_bfloat16* o2 = sentb + (size_t)sidx * HID + t * 4;
            o2[0] = __float2bfloat16(ax * inv);
            o2[1] = __float2bfloat16(ay * inv);
            o2[2] = __float2bfloat16(az * inv);
            o2[3] = __float2bfloat16(aw * inv);
        }
    } else {
        // ---- weight transpose fp32[K][N] -> bf16[N][K], one 32x32 tile ----
        float* tile = (float*)smem;           // [32][33]
        const int id0 = blk - 512;
        const float* in; __hip_bfloat16* outw; int K, N, n0, k0;
        if (id0 < 3072) { in = W1; outw = W1T; K = 768;  N = 4096;
                          n0 = (id0 & 127) * 32; k0 = (id0 >> 7) * 32; }
        else { const int id = id0 - 3072;
               in = W2; outw = W2T; K = 4096; N = 256;
               n0 = (id & 7) * 32; k0 = (id >> 3) * 32; }
        const int c = t & 31;
        const int r = t >> 5;
        #pragma unroll
        for (int i = 0; i < 32; i += 8)
            tile[(r + i) * 33 + c] = in[(size_t)(k0 + r + i) * N + n0 + c];
        __syncthreads();
        #pragma unroll
        for (int i = 0; i < 32; i += 8)
            outw[(size_t)(n0 + r + i) * K + k0 + c] = __float2bfloat16(tile[c * 33 + r + i]);
    }
}

// ---------------------------------------------------------------------------
// K2: GEMM1  x1 = GELU(sentb[512,768] @ W1T[4096,768]^T + b1), bf16 out.
// 64x64 tile, BK=64 (12 K-iters), grid (64,8)=512 blocks (2/CU).
// 4 waves in 2x2; each wave 32x32 via 2x2 MFMA x 2 k-steps = 8 MFMA/iter.
// LDS stride 72 bf16: 144B rows keep b128 16B-aligned; lane stride 36 dw
// -> 2 lanes/bank within a 16-lane phase (free per m136).
// ---------------------------------------------------------------------------
__global__ __launch_bounds__(256) void gemm1_kernel(const __hip_bfloat16* __restrict__ A,
                                                    const __hip_bfloat16* __restrict__ BT,
                                                    const float* __restrict__ bias,
                                                    __hip_bfloat16* __restrict__ out) {
    const int n0 = blockIdx.x * 64;
    const int m0 = blockIdx.y * 64;
    const int t = threadIdx.x;
    const int w = t >> 6, l = t & 63;
    const int wm = (w >> 1) * 32;
    const int wn = (w & 1) * 32;

    __shared__ __hip_bfloat16 Al[64][72];
    __shared__ __hip_bfloat16 Bl[64][72];

    floatx4 acc[2][2] = {};

    const int r  = t >> 2;            // 0..63
    const int ch = (t & 3) * 16;      // 0,16,32,48
    const __hip_bfloat16* Ag = A  + (size_t)(m0 + r) * 768 + ch;
    const __hip_bfloat16* Bg = BT + (size_t)(n0 + r) * 768 + ch;

    const int lr = l & 15;
    const int kq = (l >> 4) * 8;

    for (int k0 = 0; k0 < 768; k0 += 64) {
        short8 av0 = *(const short8*)(Ag + k0);
        short8 av1 = *(const short8*)(Ag + k0 + 8);
        short8 bv0 = *(const short8*)(Bg + k0);
        short8 bv1 = *(const short8*)(Bg + k0 + 8);
        __syncthreads();
        *(short8*)(&Al[r][ch])     = av0;
        *(short8*)(&Al[r][ch + 8]) = av1;
        *(short8*)(&Bl[r][ch])     = bv0;
        *(short8*)(&Bl[r][ch + 8]) = bv1;
        __syncthreads();

        #pragma unroll
        for (int ks = 0; ks < 64; ks += 32) {
            short8 a0 = *(const short8*)(&Al[wm + lr][ks + kq]);
            short8 a1 = *(const short8*)(&Al[wm + 16 + lr][ks + kq]);
            short8 b0 = *(const short8*)(&Bl[wn + lr][ks + kq]);
            short8 b1 = *(const short8*)(&Bl[wn + 16 + lr][ks + kq]);
            acc[0][0] = __builtin_amdgcn_mfma_f32_16x16x32_bf16(a0, b0, acc[0][0], 0, 0, 0);
            acc[0][1] = __builtin_amdgcn_mfma_f32_16x16x32_bf16(a0, b1, acc[0][1], 0, 0, 0);
            acc[1][0] = __builtin_amdgcn_mfma_f32_16x16x32_bf16(a1, b0, acc[1][0], 0, 0, 0);
            acc[1][1] = __builtin_amdgcn_mfma_f32_16x16x32_bf16(a1, b1, acc[1][1], 0, 0, 0);
        }
    }

    #pragma unroll
    for (int i = 0; i < 2; ++i) {
        #pragma unroll
        for (int j = 0; j < 2; ++j) {
            const int col  = n0 + wn + j * 16 + lr;
            const int rowb = m0 + wm + i * 16 + (l >> 4) * 4;
            const float bv = bias[col];
            #pragma unroll
            for (int rg = 0; rg < 4; ++rg) {
                float x = acc[i][j][rg] + bv;
                out[(size_t)(rowb + rg) * 4096 + col] = __float2bfloat16(gelu_exact(x));
            }
        }
    }
}

// ---------------------------------------------------------------------------
// K3: GEMM2 partials: part[s] = x1[512, 256-slice] @ W2T[256, 256-slice]^T.
// Split-K=16 (256 K each), BK=64 -> 4 K-iters. Grid (4,8,16)=512 blocks.
// ---------------------------------------------------------------------------
__global__ __launch_bounds__(256) void gemm2_kernel(const __hip_bfloat16* __restrict__ A,
                                                    const __hip_bfloat16* __restrict__ BT,
                                                    float* __restrict__ part) {
    const int n0 = blockIdx.x * 64;
    const int m0 = blockIdx.y * 64;
    const int s  = blockIdx.z;
    const int kb = s * 256;
    const int t = threadIdx.x;
    const int w = t >> 6, l = t & 63;
    const int wm = (w >> 1) * 32;
    const int wn = (w & 1) * 32;

    __shared__ __hip_bfloat16 Al[64][72];
    __shared__ __hip_bfloat16 Bl[64][72];

    floatx4 acc[2][2] = {};

    const int r  = t >> 2;
    const int ch = (t & 3) * 16;
    const __hip_bfloat16* Ag = A  + (size_t)(m0 + r) * 4096 + kb + ch;
    const __hip_bfloat16* Bg = BT + (size_t)(n0 + r) * 4096 + kb + ch;

    const int lr = l & 15;
    const int kq = (l >> 4) * 8;

    for (int k0 = 0; k0 < 256; k0 += 64) {
        short8 av0 = *(const short8*)(Ag + k0);
        short8 av1 = *(const short8*)(Ag + k0 + 8);
        short8 bv0 = *(const short8*)(Bg + k0);
        short8 bv1 = *(const short8*)(Bg + k0 + 8);
        __syncthreads();
        *(short8*)(&Al[r][ch])     = av0;
        *(short8*)(&Al[r][ch + 8]) = av1;
        *(short8*)(&Bl[r][ch])     = bv0;
        *(short8*)(&Bl[r][ch + 8]) = bv1;
        __syncthreads();

        #pragma unroll
        for (int ks = 0; ks < 64; ks += 32) {
            short8 a0 = *(const short8*)(&Al[wm + lr][ks + kq]);
            short8 a1 = *(const short8*)(&Al[wm + 16 + lr][ks + kq]);
            short8 b0 = *(const short8*)(&Bl[wn + lr][ks + kq]);
            short8 b1 = *(const short8*)(&Bl[wn + 16 + lr][ks + kq]);
            acc[0][0] = __builtin_amdgcn_mfma_f32_16x16x32_bf16(a0, b0, acc[0][0], 0, 0, 0);
            acc[0][1] = __builtin_amdgcn_mfma_f32_16x16x32_bf16(a0, b1, acc[0][1], 0, 0, 0);
            acc[1][0] = __builtin_amdgcn_mfma_f32_16x16x32_bf16(a1, b0, acc[1][0], 0, 0, 0);
            acc[1][1] = __builtin_amdgcn_mfma_f32_16x16x32_bf16(a1, b1, acc[1][1], 0, 0, 0);
        }
    }

    float* po = part + (size_t)s * 512 * 256;
    #pragma unroll
    for (int i = 0; i < 2; ++i) {
        #pragma unroll
        for (int j = 0; j < 2; ++j) {
            const int col  = n0 + wn + j * 16 + lr;
            const int rowb = m0 + wm + i * 16 + (l >> 4) * 4;
            #pragma unroll
            for (int rg = 0; rg < 4; ++rg)
                po[(size_t)(rowb + rg) * 256 + col] = acc[i][j][rg];
        }
    }
}

// ---------------------------------------------------------------------------
// K4: fused reduce(16 split-K partials) + b2 + GELU + head (W3[256,2]+b3).
// ---------------------------------------------------------------------------
__global__ __launch_bounds__(256) void rh_kernel(const float* __restrict__ part,
                                                 const float* __restrict__ b2,
                                                 const float* __restrict__ W3,
                                                 const float* __restrict__ b3,
                                                 float* __restrict__ out) {
    const int row = blockIdx.x;     // 512
    const int c = threadIdx.x;      // 256
    const int w = c >> 6, l = c & 63;

    float s = 0.f;
    #pragma unroll
    for (int k = 0; k < 16; ++k)
        s += part[((size_t)k * 512 + row) * 256 + c];
    const float x = gelu_exact(s + b2[c]);
    float y0 = x * W3[c * 2 + 0];
    float y1 = x * W3[c * 2 + 1];
    #pragma unroll
    for (int off = 32; off; off >>= 1) {
        y0 += __shfl_down(y0, off);
        y1 += __shfl_down(y1, off);
    }
    __shared__ float r0[4], r1[4];
    if (l == 0) { r0[w] = y0; r1[w] = y1; }
    __syncthreads();
    if (c == 0) out[row * 2 + 0] = r0[0] + r0[1] + r0[2] + r0[3] + b3[0];
    if (c == 1) out[row * 2 + 1] = r1[0] + r1[1] + r1[2] + r1[3] + b3[1];
}

// ---------------------------------------------------------------------------
extern "C" void kernel_launch(void* const* d_in, const int* in_sizes, int n_in,
                              void* d_out, int out_size, void* d_ws, size_t ws_size,
                              hipStream_t stream) {
    const float* hidden = (const float*)d_in[0];
    const int*   ids    = (const int*)d_in[1];
    const float* W1     = (const float*)d_in[2];
    const float* b1     = (const float*)d_in[3];
    const float* W2     = (const float*)d_in[4];
    const float* b2     = (const float*)d_in[5];
    const float* W3     = (const float*)d_in[6];
    const float* b3     = (const float*)d_in[7];
    float* out = (float*)d_out;

    char* ws = (char*)d_ws;
    __hip_bfloat16* sentb  = (__hip_bfloat16*)(ws + 0);           // 512x768 bf16
    __hip_bfloat16* W1T    = (__hip_bfloat16*)(ws + 786432);      // 4096x768 bf16
    __hip_bfloat16* W2T    = (__hip_bfloat16*)(ws + 7077888);     // 256x4096 bf16
    __hip_bfloat16* x1     = (__hip_bfloat16*)(ws + 9175040);     // 512x4096 bf16
    float* part            = (float*)(ws + 13369344);             // 16x512x256 f32
    // total ws use: ~21.8 MB

    stage1_kernel<<<4608, 256, 0, stream>>>(ids, hidden, W1, W2, W1T, W2T, sentb);
    gemm1_kernel<<<dim3(64, 8), 256, 0, stream>>>(sentb, W1T, b1, x1);
    gemm2_kernel<<<dim3(4, 8, 16), 256, 0, stream>>>(x1, W2T, part);
    rh_kernel<<<512, 256, 0, stream>>>(part, b2, W3, b3, out);
}

// Round 6
// 195.087 us; speedup vs baseline: 1.8169x; 1.0014x over previous
//
#include <hip/hip_runtime.h>
#include <hip/hip_bf16.h>

#define SEP_ID 2
#define S_LEN  4096
#define HID    768
#define MAXS   64

using short8  = __attribute__((ext_vector_type(8))) short;  // 8 bf16 (4 VGPRs)
using floatx4 = __attribute__((ext_vector_type(4))) float;  // MFMA accumulator

__device__ __forceinline__ float gelu_exact(float x) {
    return 0.5f * x * (1.0f + erff(x * 0.70710678118654752f));
}

// ---------------------------------------------------------------------------
// K1 "stage1": pool blocks [0,512) + weight-transpose blocks [512,4608).
// Pool blocks self-compute bounds from ids (shfl prefix-scan), then mean-pool
// with float4 columns and an 8-row unroll. All blocks co-resident -> weight
// traffic overlaps the pool HBM stream.
// ---------------------------------------------------------------------------
__global__ __launch_bounds__(256) void stage1_kernel(const int* __restrict__ ids,
                                                     const float* __restrict__ hidden,
                                                     const float* __restrict__ W1,
                                                     const float* __restrict__ W2,
                                                     __hip_bfloat16* __restrict__ W1T,
                                                     __hip_bfloat16* __restrict__ W2T,
                                                     __hip_bfloat16* __restrict__ sentb) {
    __shared__ __align__(16) char smem[16640];
    const int blk = blockIdx.x;
    const int t = threadIdx.x;

    if (blk < 512) {
        // ---- self-bounds ----
        int* sep_pos = (int*)smem;            // 4096 ints
        int* wtot    = sep_pos + 4096;        // 4 ints
        const int sidx = blk;
        const int b = sidx >> 6, m = sidx & 63;
        const int* row = ids + (size_t)b * S_LEN;
        const int lane = t & 63, w = t >> 6;

        int local[16]; int c = 0;
        const int base = t * 16;
        #pragma unroll
        for (int q = 0; q < 4; ++q) {
            int4 v = ((const int4*)row)[t * 4 + q];
            if (v.x == SEP_ID) local[c++] = base + q * 4 + 0;
            if (v.y == SEP_ID) local[c++] = base + q * 4 + 1;
            if (v.z == SEP_ID) local[c++] = base + q * 4 + 2;
            if (v.w == SEP_ID) local[c++] = base + q * 4 + 3;
        }
        int scan = c;                              // inclusive wave prefix
        #pragma unroll
        for (int off = 1; off < 64; off <<= 1) {
            int n = __shfl_up(scan, off);
            if (lane >= off) scan += n;
        }
        if (lane == 63) wtot[w] = scan;
        __syncthreads();
        int wbase = 0;
        for (int i = 0; i < w; ++i) wbase += wtot[i];
        const int o = wbase + scan - c;
        for (int i = 0; i < c; ++i) sep_pos[o + i] = local[i];
        __syncthreads();
        const int n_sep = wtot[0] + wtot[1] + wtot[2] + wtot[3];

        // ---- reference segment semantics ----
        int start = 0, cnt = 0;
        if (n_sep == 0) {
            if (m == 0) { start = 0; cnt = S_LEN; }
        } else if (m < n_sep) {
            if (m == 0) { start = 0; cnt = sep_pos[0] + 1; }     // includes first sep
            else { start = sep_pos[m - 1] + 1; cnt = sep_pos[m] - sep_pos[m - 1] - 1; }
        } else if (m == n_sep) {
            start = sep_pos[n_sep - 1] + 1;                      // trailing segment
            cnt = (S_LEN - 1) - start;                           // excludes token S-1
            if (cnt < 0) cnt = 0;
        }

        // ---- mean pool ----
        if (t < 192) {
            const float4* bp = (const float4*)(hidden + ((size_t)b * S_LEN + start) * HID);
            float ax = 0.f, ay = 0.f, az = 0.f, aw = 0.f;
            int i = 0;
            for (; i + 8 <= cnt; i += 8) {
                float4 v[8];
                #pragma unroll
                for (int j = 0; j < 8; ++j) v[j] = bp[(size_t)(i + j) * 192 + t];
                #pragma unroll
                for (int j = 0; j < 8; ++j) { ax += v[j].x; ay += v[j].y; az += v[j].z; aw += v[j].w; }
            }
            for (; i < cnt; ++i) {
                float4 v = bp[(size_t)i * 192 + t];
                ax += v.x; ay += v.y; az += v.z; aw += v.w;
            }
            const float inv = (cnt > 0) ? 1.0f / (float)cnt : 0.0f;
            __hip_bfloat16 h0 = __float2bfloat16(ax * inv);
            __hip_bfloat16 h1 = __float2bfloat16(ay * inv);
            __hip_bfloat16 h2 = __float2bfloat16(az * inv);
            __hip_bfloat16 h3 = __float2bfloat16(aw * inv);
            ushort4 pk;
            pk.x = *(unsigned short*)&h0; pk.y = *(unsigned short*)&h1;
            pk.z = *(unsigned short*)&h2; pk.w = *(unsigned short*)&h3;
            *(ushort4*)(sentb + (size_t)sidx * HID + t * 4) = pk;   // one 8B store
        }
    } else {
        // ---- weight transpose fp32[K][N] -> bf16[N][K], one 32x32 tile ----
        float* tile = (float*)smem;           // [32][33]
        const int id0 = blk - 512;
        const float* in; __hip_bfloat16* outw; int K, N, n0, k0;
        if (id0 < 3072) { in = W1; outw = W1T; K = 768;  N = 4096;
                          n0 = (id0 & 127) * 32; k0 = (id0 >> 7) * 32; }
        else { const int id = id0 - 3072;
               in = W2; outw = W2T; K = 4096; N = 256;
               n0 = (id & 7) * 32; k0 = (id >> 3) * 32; }
        const int c = t & 31;
        const int r = t >> 5;
        #pragma unroll
        for (int i = 0; i < 32; i += 8)
            tile[(r + i) * 33 + c] = in[(size_t)(k0 + r + i) * N + n0 + c];
        __syncthreads();
        #pragma unroll
        for (int i = 0; i < 32; i += 8)
            outw[(size_t)(n0 + r + i) * K + k0 + c] = __float2bfloat16(tile[c * 33 + r + i]);
    }
}

// ---------------------------------------------------------------------------
// K2: GEMM1  x1 = GELU(sentb[512,768] @ W1T[4096,768]^T + b1), bf16 out.
// 64x64 tile, BK=128 (6 K-iters -> half the barrier drains of BK=64),
// grid (64,8)=512 blocks (2/CU). 4 waves 2x2; each wave 32x32 via 2x2 MFMA
// x 4 k-steps = 16 MFMA/iter. LDS stride 136 bf16 (272B, 16B-aligned, lane
// stride 68 dw == 4 mod 32 -> <=2-way, free per m136).
// Epilogue bounces through LDS for coalesced 16B stores.
// ---------------------------------------------------------------------------
__global__ __launch_bounds__(256) void gemm1_kernel(const __hip_bfloat16* __restrict__ A,
                                                    const __hip_bfloat16* __restrict__ BT,
                                                    const float* __restrict__ bias,
                                                    __hip_bfloat16* __restrict__ out) {
    const int n0 = blockIdx.x * 64;
    const int m0 = blockIdx.y * 64;
    const int t = threadIdx.x;
    const int w = t >> 6, l = t & 63;
    const int wm = (w >> 1) * 32;
    const int wn = (w & 1) * 32;

    __shared__ __hip_bfloat16 Al[64][136];
    __shared__ __hip_bfloat16 Bl[64][136];

    floatx4 acc[2][2] = {};

    const int r  = t >> 2;            // 0..63
    const int ch = (t & 3) * 32;      // 0,32,64,96  (each thread: 64B contiguous)
    const __hip_bfloat16* Ag = A  + (size_t)(m0 + r) * 768 + ch;
    const __hip_bfloat16* Bg = BT + (size_t)(n0 + r) * 768 + ch;

    const int lr = l & 15;
    const int kq = (l >> 4) * 8;

    for (int k0 = 0; k0 < 768; k0 += 128) {
        short8 av[4], bv[4];
        #pragma unroll
        for (int q = 0; q < 4; ++q) {
            av[q] = *(const short8*)(Ag + k0 + q * 8);
            bv[q] = *(const short8*)(Bg + k0 + q * 8);
        }
        __syncthreads();
        #pragma unroll
        for (int q = 0; q < 4; ++q) {
            *(short8*)(&Al[r][ch + q * 8]) = av[q];
            *(short8*)(&Bl[r][ch + q * 8]) = bv[q];
        }
        __syncthreads();

        #pragma unroll
        for (int ks = 0; ks < 128; ks += 32) {
            short8 a0 = *(const short8*)(&Al[wm + lr][ks + kq]);
            short8 a1 = *(const short8*)(&Al[wm + 16 + lr][ks + kq]);
            short8 b0 = *(const short8*)(&Bl[wn + lr][ks + kq]);
            short8 b1 = *(const short8*)(&Bl[wn + 16 + lr][ks + kq]);
            acc[0][0] = __builtin_amdgcn_mfma_f32_16x16x32_bf16(a0, b0, acc[0][0], 0, 0, 0);
            acc[0][1] = __builtin_amdgcn_mfma_f32_16x16x32_bf16(a0, b1, acc[0][1], 0, 0, 0);
            acc[1][0] = __builtin_amdgcn_mfma_f32_16x16x32_bf16(a1, b0, acc[1][0], 0, 0, 0);
            acc[1][1] = __builtin_amdgcn_mfma_f32_16x16x32_bf16(a1, b1, acc[1][1], 0, 0, 0);
        }
    }

    // ---- epilogue: bias + GELU -> LDS [64][72] -> coalesced b128 stores ----
    __syncthreads();                            // all frag reads done
    __hip_bfloat16* E = &Al[0][0];              // reuse, stride 72
    #pragma unroll
    for (int i = 0; i < 2; ++i) {
        #pragma unroll
        for (int j = 0; j < 2; ++j) {
            const int cl = wn + j * 16 + lr;
            const float bv = bias[n0 + cl];
            #pragma unroll
            for (int rg = 0; rg < 4; ++rg) {
                const int rl = wm + i * 16 + (l >> 4) * 4 + rg;
                float x = acc[i][j][rg] + bv;
                E[rl * 72 + cl] = __float2bfloat16(gelu_exact(x));
            }
        }
    }
    __syncthreads();
    {
        const int rr  = t >> 2;                 // 0..63
        const int seg = (t & 3) * 16;           // 16 cols per 32B segment
        short8 v0 = *(const short8*)(&E[rr * 72 + seg]);
        short8 v1 = *(const short8*)(&E[rr * 72 + seg + 8]);
        __hip_bfloat16* op = out + (size_t)(m0 + rr) * 4096 + n0 + seg;
        *(short8*)(op)     = v0;
        *(short8*)(op + 8) = v1;
    }
}

// ---------------------------------------------------------------------------
// K3: GEMM2 partials: part[s] = x1[512, 512-slice] @ W2T[256, 512-slice]^T.
// Split-K=8 (512 K each), BK=128 -> 4 K-iters. Grid (4,8,8)=256 blocks.
// ---------------------------------------------------------------------------
__global__ __launch_bounds__(256) void gemm2_kernel(const __hip_bfloat16* __restrict__ A,
                                                    const __hip_bfloat16* __restrict__ BT,
                                                    float* __restrict__ part) {
    const int n0 = blockIdx.x * 64;
    const int m0 = blockIdx.y * 64;
    const int s  = blockIdx.z;
    const int kb = s * 512;
    const int t = threadIdx.x;
    const int w = t >> 6, l = t & 63;
    const int wm = (w >> 1) * 32;
    const int wn = (w & 1) * 32;

    __shared__ __hip_bfloat16 Al[64][136];
    __shared__ __hip_bfloat16 Bl[64][136];

    floatx4 acc[2][2] = {};

    const int r  = t >> 2;
    const int ch = (t & 3) * 32;
    const __hip_bfloat16* Ag = A  + (size_t)(m0 + r) * 4096 + kb + ch;
    const __hip_bfloat16* Bg = BT + (size_t)(n0 + r) * 4096 + kb + ch;

    const int lr = l & 15;
    const int kq = (l >> 4) * 8;

    for (int k0 = 0; k0 < 512; k0 += 128) {
        short8 av[4], bv[4];
        #pragma unroll
        for (int q = 0; q < 4; ++q) {
            av[q] = *(const short8*)(Ag + k0 + q * 8);
            bv[q] = *(const short8*)(Bg + k0 + q * 8);
        }
        __syncthreads();
        #pragma unroll
        for (int q = 0; q < 4; ++q) {
            *(short8*)(&Al[r][ch + q * 8]) = av[q];
            *(short8*)(&Bl[r][ch + q * 8]) = bv[q];
        }
        __syncthreads();

        #pragma unroll
        for (int ks = 0; ks < 128; ks += 32) {
            short8 a0 = *(const short8*)(&Al[wm + lr][ks + kq]);
            short8 a1 = *(const short8*)(&Al[wm + 16 + lr][ks + kq]);
            short8 b0 = *(const short8*)(&Bl[wn + lr][ks + kq]);
            short8 b1 = *(const short8*)(&Bl[wn + 16 + lr][ks + kq]);
            acc[0][0] = __builtin_amdgcn_mfma_f32_16x16x32_bf16(a0, b0, acc[0][0], 0, 0, 0);
            acc[0][1] = __builtin_amdgcn_mfma_f32_16x16x32_bf16(a0, b1, acc[0][1], 0, 0, 0);
            acc[1][0] = __builtin_amdgcn_mfma_f32_16x16x32_bf16(a1, b0, acc[1][0], 0, 0, 0);
            acc[1][1] = __builtin_amdgcn_mfma_f32_16x16x32_bf16(a1, b1, acc[1][1], 0, 0, 0);
        }
    }

    float* po = part + (size_t)s * 512 * 256;
    #pragma unroll
    for (int i = 0; i < 2; ++i) {
        #pragma unroll
        for (int j = 0; j < 2; ++j) {
            const int col  = n0 + wn + j * 16 + lr;
            const int rowb = m0 + wm + i * 16 + (l >> 4) * 4;
            #pragma unroll
            for (int rg = 0; rg < 4; ++rg)
                po[(size_t)(rowb + rg) * 256 + col] = acc[i][j][rg];
        }
    }
}

// ---------------------------------------------------------------------------
// K4: fused reduce(8 split-K partials) + b2 + GELU + head (W3[256,2]+b3).
// ---------------------------------------------------------------------------
__global__ __launch_bounds__(256) void rh_kernel(const float* __restrict__ part,
                                                 const float* __restrict__ b2,
                                                 const float* __restrict__ W3,
                                                 const float* __restrict__ b3,
                                                 float* __restrict__ out) {
    const int row = blockIdx.x;     // 512
    const int c = threadIdx.x;      // 256
    const int w = c >> 6, l = c & 63;

    float s = 0.f;
    #pragma unroll
    for (int k = 0; k < 8; ++k)
        s += part[((size_t)k * 512 + row) * 256 + c];
    const float x = gelu_exact(s + b2[c]);
    float y0 = x * W3[c * 2 + 0];
    float y1 = x * W3[c * 2 + 1];
    #pragma unroll
    for (int off = 32; off; off >>= 1) {
        y0 += __shfl_down(y0, off);
        y1 += __shfl_down(y1, off);
    }
    __shared__ float r0[4], r1[4];
    if (l == 0) { r0[w] = y0; r1[w] = y1; }
    __syncthreads();
    if (c == 0) out[row * 2 + 0] = r0[0] + r0[1] + r0[2] + r0[3] + b3[0];
    if (c == 1) out[row * 2 + 1] = r1[0] + r1[1] + r1[2] + r1[3] + b3[1];
}

// ---------------------------------------------------------------------------
extern "C" void kernel_launch(void* const* d_in, const int* in_sizes, int n_in,
                              void* d_out, int out_size, void* d_ws, size_t ws_size,
                              hipStream_t stream) {
    const float* hidden = (const float*)d_in[0];
    const int*   ids    = (const int*)d_in[1];
    const float* W1     = (const float*)d_in[2];
    const float* b1     = (const float*)d_in[3];
    const float* W2     = (const float*)d_in[4];
    const float* b2     = (const float*)d_in[5];
    const float* W3     = (const float*)d_in[6];
    const float* b3     = (const float*)d_in[7];
    float* out = (float*)d_out;

    char* ws = (char*)d_ws;
    __hip_bfloat16* sentb  = (__hip_bfloat16*)(ws + 0);           // 512x768 bf16
    __hip_bfloat16* W1T    = (__hip_bfloat16*)(ws + 786432);      // 4096x768 bf16
    __hip_bfloat16* W2T    = (__hip_bfloat16*)(ws + 7077888);     // 256x4096 bf16
    __hip_bfloat16* x1     = (__hip_bfloat16*)(ws + 9175040);     // 512x4096 bf16
    float* part            = (float*)(ws + 13369344);             // 8x512x256 f32
    // total ws use: ~17.6 MB

    stage1_kernel<<<4608, 256, 0, stream>>>(ids, hidden, W1, W2, W1T, W2T, sentb);
    gemm1_kernel<<<dim3(64, 8), 256, 0, stream>>>(sentb, W1T, b1, x1);
    gemm2_kernel<<<dim3(4, 8, 8), 256, 0, stream>>>(x1, W2T, part);
    rh_kernel<<<512, 256, 0, stream>>>(part, b2, W3, b3, out);
}